// Round 1
// baseline (794.040 us; speedup 1.0000x reference)
//
#include <hip/hip_runtime.h>
#include <cmath>

#define Bsz   128
#define INsz  1024
#define OUTsz 1024
#define ZDsz  128

typedef __bf16 bf16x8 __attribute__((ext_vector_type(8)));
typedef float  floatx4 __attribute__((ext_vector_type(4)));

// ---------------------------------------------------------------------------
// Kernel 1: small terms (fp32, exact):
//   out[b,o] = a*sum_i W[o,i]x[b,i] + (1-a)*sum_i dwb[o*IN+i]x[b,i]
//            + (1-a)*sum_z dbW[o,z]z[b,z] + a*bb[o] + (1-a)*dbb[o]
// grid 256 blocks x 512 threads; thread: b = t&127, osub = t>>7 (wave-uniform)
// ---------------------------------------------------------------------------
__global__ __launch_bounds__(512) void small_terms_kernel(
    const float* __restrict__ x, const float* __restrict__ z,
    const float* __restrict__ W, const float* __restrict__ dwb,
    const float* __restrict__ bb, const float* __restrict__ dbW,
    const float* __restrict__ dbb, const float* __restrict__ s,
    float* __restrict__ out)
{
    int t = threadIdx.x;
    int b = t & 127;
    int osub = __builtin_amdgcn_readfirstlane(t >> 7);   // wave-uniform -> s_loads for W rows
    int o = blockIdx.x * 4 + osub;

    float a = 0.2f / (1.f + __expf(-s[0]));
    float one_a = 1.f - a;

    const float4* W4 = reinterpret_cast<const float4*>(W   + (size_t)o * INsz);
    const float4* d4 = reinterpret_cast<const float4*>(dwb + (size_t)o * INsz);
    const float4* x4 = reinterpret_cast<const float4*>(x   + (size_t)b * INsz);

    float acc = a * bb[o] + one_a * dbb[o];
    #pragma unroll 4
    for (int i = 0; i < INsz / 4; ++i) {
        float4 wv = W4[i], dv = d4[i], xv = x4[i];
        acc += (a * wv.x + one_a * dv.x) * xv.x;
        acc += (a * wv.y + one_a * dv.y) * xv.y;
        acc += (a * wv.z + one_a * dv.z) * xv.z;
        acc += (a * wv.w + one_a * dv.w) * xv.w;
    }

    const float4* db4 = reinterpret_cast<const float4*>(dbW + (size_t)o * ZDsz);
    const float4* z4  = reinterpret_cast<const float4*>(z   + (size_t)b * ZDsz);
    float accz = 0.f;
    #pragma unroll 4
    for (int i = 0; i < ZDsz / 4; ++i) {
        float4 wv = db4[i], zv = z4[i];
        accz += wv.x * zv.x + wv.y * zv.y + wv.z * zv.z + wv.w * zv.w;
    }
    acc += one_a * accz;

    out[(size_t)b * OUTsz + o] = acc;
}

// ---------------------------------------------------------------------------
// Kernel 2: main term via bf16 MFMA, streaming dw_W exactly once (512 MB).
//   P[i-row, b] = sum_z dwW[o, i, z] * z[b, z]   (16x16x32 MFMA, A=dwW, B=z^T)
//   out[b,o]   += sum_i P[i,b] * (1-a)*x[b,i]    (fp32 epilogue on C-frags)
// grid (64 o-tiles, 4 i-splits) x 256 threads. B-frags (z^T) register-resident.
// C/D layout: col=lane&15, row=quad*4+reg  [verified m89/m91]
// A layout:   A[m=lane&15][k=quad*8+j]     [verified m118-122]
// ---------------------------------------------------------------------------
__global__ __launch_bounds__(256, 1) void hyper_main_kernel(
    const float* __restrict__ x, const float* __restrict__ z,
    const float* __restrict__ dwW, const float* __restrict__ s,
    float* __restrict__ out)
{
    __shared__ __align__(16) __bf16 zt[128 * 136];   // z as bf16, row stride 136 (272B, 16B-aligned, 2-way-bank-free)
    __shared__ __align__(16) float  xt[128 * 20];    // x-tile * (1-a), row stride 20 (bank-spread)
    __shared__ float oacc[16 * 128];                 // [o_local][b] fp32 accumulator

    int t    = threadIdx.x;
    int lane = t & 63;
    int wave = t >> 6;
    int quad = lane >> 4;
    int l15  = lane & 15;

    float one_a = 1.f - 0.2f / (1.f + __expf(-s[0]));

    // stage z -> zt (fp32 -> bf16), 64 elems/thread
    {
        int b = t >> 1;
        int half = (t & 1) * 64;
        const float4* zrow = reinterpret_cast<const float4*>(z + (size_t)b * ZDsz + half);
        __bf16* dst = &zt[b * 136 + half];
        #pragma unroll
        for (int j = 0; j < 16; ++j) {
            float4 v = zrow[j];
            dst[j*4+0] = (__bf16)v.x; dst[j*4+1] = (__bf16)v.y;
            dst[j*4+2] = (__bf16)v.z; dst[j*4+3] = (__bf16)v.w;
        }
    }
    #pragma unroll
    for (int j = 0; j < 8; ++j) oacc[t * 8 + j] = 0.f;
    __syncthreads();

    // resident B-fragments: B[k=z][n=b] = z[b,z]; frag: n=lane&15, k=quad*8+j
    bf16x8 bfrag[8][4];
    #pragma unroll
    for (int sj = 0; sj < 8; ++sj)
        #pragma unroll
        for (int k = 0; k < 4; ++k)
            bfrag[sj][k] = *reinterpret_cast<const bf16x8*>(
                &zt[(sj * 16 + l15) * 136 + k * 32 + quad * 8]);

    int otile = blockIdx.x * 16;
    int ibase = blockIdx.y * 256;

    for (int it = 0; it < 16; ++it) {
        int i0 = ibase + it * 16;
        // stage xt[b][ii] = (1-a)*x[b, i0+ii]
        {
            int b = t >> 1;
            int part = (t & 1) * 8;
            const float* xr = x + (size_t)b * INsz + i0 + part;
            float* dst = &xt[b * 20 + part];
            #pragma unroll
            for (int j = 0; j < 8; ++j) dst[j] = one_a * xr[j];
        }
        __syncthreads();

        #pragma unroll 1
        for (int c = 0; c < 4; ++c) {
            int o = otile + wave * 4 + c;                       // each o owned by one wave
            const float* abase = dwW + ((size_t)o * INsz + i0 + l15) * ZDsz + quad * 8;

            float av[4][8];
            #pragma unroll
            for (int k = 0; k < 4; ++k) {                        // 8 x dwordx4, contiguous 8KB/wave
                float4 lo = *reinterpret_cast<const float4*>(abase + k * 32);
                float4 hi = *reinterpret_cast<const float4*>(abase + k * 32 + 4);
                av[k][0]=lo.x; av[k][1]=lo.y; av[k][2]=lo.z; av[k][3]=lo.w;
                av[k][4]=hi.x; av[k][5]=hi.y; av[k][6]=hi.z; av[k][7]=hi.w;
            }
            bf16x8 afrag[4];
            #pragma unroll
            for (int k = 0; k < 4; ++k)
                #pragma unroll
                for (int j = 0; j < 8; ++j) afrag[k][j] = (__bf16)av[k][j];

            #pragma unroll
            for (int sj = 0; sj < 8; ++sj) {
                floatx4 cf = {0.f, 0.f, 0.f, 0.f};
                #pragma unroll
                for (int k = 0; k < 4; ++k)
                    cf = __builtin_amdgcn_mfma_f32_16x16x32_bf16(afrag[k], bfrag[sj][k], cf, 0, 0, 0);
                // weight by (1-a)*x[b=sj*16+l15, i0+quad*4+reg], reduce over 16 rows
                const floatx4 xv = *reinterpret_cast<const floatx4*>(&xt[(sj * 16 + l15) * 20 + quad * 4]);
                float p = cf[0]*xv[0] + cf[1]*xv[1] + cf[2]*xv[2] + cf[3]*xv[3];
                p += __shfl_xor(p, 16);
                p += __shfl_xor(p, 32);
                if (lane < 16) oacc[(wave * 4 + c) * 128 + sj * 16 + l15] += p;
            }
        }
        __syncthreads();
    }

    // flush block's partial tile: 4 i-split blocks per o -> atomicAdd
    {
        int b = t >> 1;
        int og = (t & 1) * 8;
        #pragma unroll
        for (int j = 0; j < 8; ++j)
            atomicAdd(&out[(size_t)b * OUTsz + otile + og + j], oacc[(og + j) * 128 + b]);
    }
}

extern "C" void kernel_launch(void* const* d_in, const int* in_sizes, int n_in,
                              void* d_out, int out_size, void* d_ws, size_t ws_size,
                              hipStream_t stream) {
    (void)in_sizes; (void)n_in; (void)d_ws; (void)ws_size; (void)out_size;
    const float* x   = (const float*)d_in[0];
    const float* z   = (const float*)d_in[1];
    const float* W   = (const float*)d_in[2];
    const float* dwW = (const float*)d_in[3];
    const float* dwb = (const float*)d_in[4];
    const float* bb  = (const float*)d_in[5];
    const float* dbW = (const float*)d_in[6];
    const float* dbb = (const float*)d_in[7];
    const float* s   = (const float*)d_in[8];
    float* out = (float*)d_out;

    small_terms_kernel<<<dim3(OUTsz / 4), 512, 0, stream>>>(x, z, W, dwb, bb, dbW, dbb, s, out);
    hyper_main_kernel<<<dim3(OUTsz / 16, 4), 256, 0, stream>>>(x, z, dwW, s, out);
}

// Round 2
// 737.426 us; speedup vs baseline: 1.0768x; 1.0768x over previous
//
#include <hip/hip_runtime.h>
#include <cmath>

#define Bsz   128
#define INsz  1024
#define OUTsz 1024
#define ZDsz  128

typedef __bf16 bf16x8 __attribute__((ext_vector_type(8)));
typedef float  floatx4 __attribute__((ext_vector_type(4)));

// ---------------------------------------------------------------------------
// Single fused kernel.
//   P[i,b]      = sum_z dwW[o,i,z] * z[b,z]          (bf16 MFMA 16x16x32, A=dwW, B=z^T)
//   w_extra[i]  = dwb[o,i] + (a/(1-a))*W[o,i]        (fp32, b-independent)
//   oacc[o,b]  += sum_i (P[i,b]+w_extra[i]) * x[b,i] (fp32 epilogue, shfl-reduce)
//   (y==0 only) oacc[o,b] += (z.dbW^T)[b,o] + ratio*bb[o] + dbb[o]   (1 extra MFMA)
//   out[b,o]   += (1-a) * oacc[o,b]                  (atomicAdd; out pre-zeroed)
// grid (64 o-tiles, 8 i-splits) x 256 thr = 512 blocks = 2 blocks/CU = 2 w/SIMD.
// K-loop is barrier-free: z-frags register-resident, x read via L1.
// C/D layout: col=lane&15, row=quad*4+reg  [verified m89/m91, and R1 passed]
// ---------------------------------------------------------------------------
__global__ __launch_bounds__(256, 2) void hyper_fused_kernel(
    const float* __restrict__ x, const float* __restrict__ z,
    const float* __restrict__ W, const float* __restrict__ dwW,
    const float* __restrict__ dwb, const float* __restrict__ bb,
    const float* __restrict__ dbW, const float* __restrict__ dbb,
    const float* __restrict__ s, float* __restrict__ out)
{
    __shared__ __align__(16) __bf16 zt[128 * 136];   // z as bf16, row stride 136
    __shared__ float oacc[16 * 128];                 // [o_local][b] fp32 accumulator

    int t    = threadIdx.x;
    int lane = t & 63;
    int wave = t >> 6;
    int quad = lane >> 4;
    int l15  = lane & 15;

    float a     = 0.2f / (1.f + __expf(-s[0]));
    float one_a = 1.f - a;
    float ratio = a / one_a;

    // stage z -> zt (fp32 -> bf16), 64 elems/thread
    {
        int b = t >> 1;
        int half = (t & 1) * 64;
        const float4* zrow = reinterpret_cast<const float4*>(z + (size_t)b * ZDsz + half);
        __bf16* dst = &zt[b * 136 + half];
        #pragma unroll
        for (int j = 0; j < 16; ++j) {
            float4 v = zrow[j];
            dst[j*4+0] = (__bf16)v.x; dst[j*4+1] = (__bf16)v.y;
            dst[j*4+2] = (__bf16)v.z; dst[j*4+3] = (__bf16)v.w;
        }
    }
    #pragma unroll
    for (int j = 0; j < 8; ++j) oacc[t * 8 + j] = 0.f;
    __syncthreads();

    // resident B-fragments: B[k=z][n=b] = z[b,z]; frag: n=lane&15, k=quad*8+j
    bf16x8 bfrag[8][4];
    #pragma unroll
    for (int sj = 0; sj < 8; ++sj)
        #pragma unroll
        for (int k = 0; k < 4; ++k)
            bfrag[sj][k] = *reinterpret_cast<const bf16x8*>(
                &zt[(sj * 16 + l15) * 136 + k * 32 + quad * 8]);

    int otile = blockIdx.x * 16;
    int ibase = blockIdx.y * 128;

    // ---- barrier-free K-loop: 8 it x 4 c = 32 iterations, 8KB A-stream each
    for (int it = 0; it < 8; ++it) {
        int i0 = ibase + it * 16;
        #pragma unroll 1
        for (int c = 0; c < 4; ++c) {
            int o = otile + wave * 4 + c;                       // each o owned by one wave

            // broadcast loads for the b-independent extra term (1 line each)
            float4 Wv = *reinterpret_cast<const float4*>(W   + (size_t)o * INsz + i0 + quad * 4);
            float4 Dv = *reinterpret_cast<const float4*>(dwb + (size_t)o * INsz + i0 + quad * 4);

            // A-tile: 16 rows (i0+l15) x 128 z, 8KB contiguous per wave
            const float* abase = dwW + ((size_t)o * INsz + i0 + l15) * ZDsz + quad * 8;
            bf16x8 afrag[4];
            #pragma unroll
            for (int k = 0; k < 4; ++k) {
                float4 lo = *reinterpret_cast<const float4*>(abase + k * 32);
                float4 hi = *reinterpret_cast<const float4*>(abase + k * 32 + 4);
                afrag[k][0]=(__bf16)lo.x; afrag[k][1]=(__bf16)lo.y;
                afrag[k][2]=(__bf16)lo.z; afrag[k][3]=(__bf16)lo.w;
                afrag[k][4]=(__bf16)hi.x; afrag[k][5]=(__bf16)hi.y;
                afrag[k][6]=(__bf16)hi.z; afrag[k][7]=(__bf16)hi.w;
            }

            float wex0 = Dv.x + ratio * Wv.x;
            float wex1 = Dv.y + ratio * Wv.y;
            float wex2 = Dv.z + ratio * Wv.z;
            float wex3 = Dv.w + ratio * Wv.w;

            #pragma unroll
            for (int sj = 0; sj < 8; ++sj) {
                floatx4 cf = {0.f, 0.f, 0.f, 0.f};
                #pragma unroll
                for (int k = 0; k < 4; ++k)
                    cf = __builtin_amdgcn_mfma_f32_16x16x32_bf16(afrag[k], bfrag[sj][k], cf, 0, 0, 0);
                // x[b = sj*16+l15, i0+quad*4+r] straight from global (L1-hot after c=0)
                const floatx4 xv = *reinterpret_cast<const floatx4*>(
                    x + (size_t)(sj * 16 + l15) * INsz + i0 + quad * 4);
                float p = (cf[0] + wex0) * xv[0] + (cf[1] + wex1) * xv[1]
                        + (cf[2] + wex2) * xv[2] + (cf[3] + wex3) * xv[3];
                p += __shfl_xor(p, 16);
                p += __shfl_xor(p, 32);
                if (lane < 16) oacc[(wave * 4 + c) * 128 + sj * 16 + l15] += p;
            }
        }
    }

    // ---- dbW MFMA + bias (only the y==0 i-split block contributes these)
    if (blockIdx.y == 0) {
        __syncthreads();    // main-loop oacc writes use a different row pattern
        const float* abase = dbW + (size_t)(otile + l15) * ZDsz + quad * 8;
        bf16x8 afrag[4];
        #pragma unroll
        for (int k = 0; k < 4; ++k) {
            float4 lo = *reinterpret_cast<const float4*>(abase + k * 32);
            float4 hi = *reinterpret_cast<const float4*>(abase + k * 32 + 4);
            afrag[k][0]=(__bf16)lo.x; afrag[k][1]=(__bf16)lo.y;
            afrag[k][2]=(__bf16)lo.z; afrag[k][3]=(__bf16)lo.w;
            afrag[k][4]=(__bf16)hi.x; afrag[k][5]=(__bf16)hi.y;
            afrag[k][6]=(__bf16)hi.z; afrag[k][7]=(__bf16)hi.w;
        }
        float4 bbv  = *reinterpret_cast<const float4*>(bb  + otile + quad * 4);
        float4 dbbv = *reinterpret_cast<const float4*>(dbb + otile + quad * 4);
        float bias0 = ratio * bbv.x + dbbv.x, bias1 = ratio * bbv.y + dbbv.y;
        float bias2 = ratio * bbv.z + dbbv.z, bias3 = ratio * bbv.w + dbbv.w;
        #pragma unroll
        for (int u = 0; u < 2; ++u) {
            int sj = wave * 2 + u;
            floatx4 cf = {0.f, 0.f, 0.f, 0.f};
            #pragma unroll
            for (int k = 0; k < 4; ++k)
                cf = __builtin_amdgcn_mfma_f32_16x16x32_bf16(afrag[k], bfrag[sj][k], cf, 0, 0, 0);
            // D[row=otile+quad*4+r][col b=sj*16+l15]
            oacc[(quad * 4 + 0) * 128 + sj * 16 + l15] += cf[0] + bias0;
            oacc[(quad * 4 + 1) * 128 + sj * 16 + l15] += cf[1] + bias1;
            oacc[(quad * 4 + 2) * 128 + sj * 16 + l15] += cf[2] + bias2;
            oacc[(quad * 4 + 3) * 128 + sj * 16 + l15] += cf[3] + bias3;
        }
    }
    __syncthreads();

    // flush: 8 i-split blocks add into out (pre-zeroed by memset)
    {
        int b = t >> 1;
        int og = (t & 1) * 8;
        #pragma unroll
        for (int j = 0; j < 8; ++j)
            atomicAdd(&out[(size_t)b * OUTsz + otile + og + j],
                      one_a * oacc[(og + j) * 128 + b]);
    }
}

extern "C" void kernel_launch(void* const* d_in, const int* in_sizes, int n_in,
                              void* d_out, int out_size, void* d_ws, size_t ws_size,
                              hipStream_t stream) {
    (void)in_sizes; (void)n_in; (void)d_ws; (void)ws_size;
    const float* x   = (const float*)d_in[0];
    const float* z   = (const float*)d_in[1];
    const float* W   = (const float*)d_in[2];
    const float* dwW = (const float*)d_in[3];
    const float* dwb = (const float*)d_in[4];
    const float* bb  = (const float*)d_in[5];
    const float* dbW = (const float*)d_in[6];
    const float* dbb = (const float*)d_in[7];
    const float* s   = (const float*)d_in[8];
    float* out = (float*)d_out;

    hipMemsetAsync(out, 0, (size_t)out_size * sizeof(float), stream);
    hyper_fused_kernel<<<dim3(OUTsz / 16, 8), 256, 0, stream>>>(
        x, z, W, dwW, dwb, bb, dbW, dbb, s, out);
}

// Round 3
// 730.495 us; speedup vs baseline: 1.0870x; 1.0095x over previous
//
#include <hip/hip_runtime.h>
#include <cmath>

#define Bsz   128
#define INsz  1024
#define OUTsz 1024
#define ZDsz  128

typedef __bf16 bf16x8 __attribute__((ext_vector_type(8)));
typedef __bf16 bf16x4 __attribute__((ext_vector_type(4)));
typedef float  floatx4 __attribute__((ext_vector_type(4)));

// ---------------------------------------------------------------------------
// Single fused kernel, R3.
//   P[i,b]      = sum_z dwW[o,i,z] * z[b,z]          (bf16 MFMA 16x16x32, A=dwW, B=z^T)
//   w_extra[i]  = dwb[o,i] + (a/(1-a))*W[o,i]        (fp32, b-independent)
//   oacc[o,b]  += sum_i (P[i,b]+w_extra[i]) * x[b,i] (x from LDS as bf16)
//   (y==0 only) oacc[o,b] += (z.dbW^T)[b,o] + ratio*bb[o] + dbb[o]
//   out[b,o]   += (1-a) * oacc[o,b]                  (atomicAdd; out pre-zeroed)
// grid (64 o-tiles, 8 i-splits) x 256 thr = 512 blocks = 2 blocks/CU.
// R3 changes vs R2: coalesced staging (32 lanes = one 512B row), x-tile in LDS
// (kills 64-line divergent global reads in epilogue), A-stream prefetched one
// iteration ahead (breaks the load->cvt->MFMA convoy).
// smem union: phase 1 holds z (bf16), dead after bfrag reg-load; phase 2 x-tile.
// ---------------------------------------------------------------------------
__global__ __launch_bounds__(256, 2) void hyper_fused_kernel(
    const float* __restrict__ x, const float* __restrict__ z,
    const float* __restrict__ W, const float* __restrict__ dwW,
    const float* __restrict__ dwb, const float* __restrict__ bb,
    const float* __restrict__ dbW, const float* __restrict__ dbb,
    const float* __restrict__ s, float* __restrict__ out)
{
    __shared__ __align__(16) __bf16 smem[128 * 136];  // z (phase 1) then x-tile (phase 2)
    __shared__ float oacc[16 * 128];                  // [o_local][b] fp32 accumulator

    int t    = threadIdx.x;
    int lane = t & 63;
    int wave = t >> 6;
    int quad = lane >> 4;
    int l15  = lane & 15;
    int l31  = lane & 31;
    int rowp = lane >> 5;

    float a     = 0.2f / (1.f + __expf(-s[0]));
    float one_a = 1.f - a;
    float ratio = a / one_a;

    int otile = blockIdx.x * 16;
    int ibase = blockIdx.y * 128;

    // ---- phase 1: stage z -> smem (bf16), coalesced: 2 rows x 512B per instr
    #pragma unroll
    for (int j = 0; j < 16; ++j) {
        int r  = wave * 32 + 2 * j + rowp;
        int cc = l31 * 4;
        float4 v = *reinterpret_cast<const float4*>(z + (size_t)r * ZDsz + cc);
        __bf16* d = &smem[r * 136 + cc];
        d[0] = (__bf16)v.x; d[1] = (__bf16)v.y; d[2] = (__bf16)v.z; d[3] = (__bf16)v.w;
    }
    #pragma unroll
    for (int j = 0; j < 8; ++j) oacc[t * 8 + j] = 0.f;
    __syncthreads();

    // resident B-fragments: B[k=z][n=b] = z[b,z]; frag: n=lane&15, k=quad*8+j
    bf16x8 bfrag[8][4];
    #pragma unroll
    for (int sj = 0; sj < 8; ++sj)
        #pragma unroll
        for (int k = 0; k < 4; ++k)
            bfrag[sj][k] = *reinterpret_cast<const bf16x8*>(
                &smem[(sj * 16 + l15) * 136 + k * 32 + quad * 8]);
    __syncthreads();   // bfrag reg-loads complete before smem is overwritten

    // ---- phase 2: stage x-tile (this block's 128 i-cols) -> smem (bf16)
    #pragma unroll
    for (int j = 0; j < 16; ++j) {
        int r  = wave * 32 + 2 * j + rowp;
        int cc = l31 * 4;
        float4 v = *reinterpret_cast<const float4*>(x + (size_t)r * INsz + ibase + cc);
        __bf16* d = &smem[r * 136 + cc];
        d[0] = (__bf16)v.x; d[1] = (__bf16)v.y; d[2] = (__bf16)v.z; d[3] = (__bf16)v.w;
    }
    __syncthreads();

    // ---- prefetched A-stream state
    float4 avlo[4], avhi[4], Wv, Dv;
    auto load_iter = [&](int idx) {
        int it = idx >> 2, c = idx & 3;
        int i0 = ibase + it * 16;
        int o  = otile + wave * 4 + c;
        const float* ab = dwW + ((size_t)o * INsz + i0 + l15) * ZDsz + quad * 8;
        #pragma unroll
        for (int k = 0; k < 4; ++k) {
            avlo[k] = *reinterpret_cast<const float4*>(ab + k * 32);
            avhi[k] = *reinterpret_cast<const float4*>(ab + k * 32 + 4);
        }
        Wv = *reinterpret_cast<const float4*>(W   + (size_t)o * INsz + i0 + quad * 4);
        Dv = *reinterpret_cast<const float4*>(dwb + (size_t)o * INsz + i0 + quad * 4);
    };
    load_iter(0);

    // ---- barrier-free K-loop: 32 flat iterations (8 i-steps x 4 o-per-wave)
    #pragma unroll 1
    for (int idx = 0; idx < 32; ++idx) {
        int it = idx >> 2, c = idx & 3;

        // consume prefetched data -> afrag / wex
        bf16x8 afrag[4];
        #pragma unroll
        for (int k = 0; k < 4; ++k) {
            afrag[k][0]=(__bf16)avlo[k].x; afrag[k][1]=(__bf16)avlo[k].y;
            afrag[k][2]=(__bf16)avlo[k].z; afrag[k][3]=(__bf16)avlo[k].w;
            afrag[k][4]=(__bf16)avhi[k].x; afrag[k][5]=(__bf16)avhi[k].y;
            afrag[k][6]=(__bf16)avhi[k].z; afrag[k][7]=(__bf16)avhi[k].w;
        }
        float wex0 = Dv.x + ratio * Wv.x;
        float wex1 = Dv.y + ratio * Wv.y;
        float wex2 = Dv.z + ratio * Wv.z;
        float wex3 = Dv.w + ratio * Wv.w;

        if (idx < 31) load_iter(idx + 1);   // overlap next A-stream with MFMA+epilogue

        #pragma unroll
        for (int sj = 0; sj < 8; ++sj) {
            floatx4 cf = {0.f, 0.f, 0.f, 0.f};
            #pragma unroll
            for (int k = 0; k < 4; ++k)
                cf = __builtin_amdgcn_mfma_f32_16x16x32_bf16(afrag[k], bfrag[sj][k], cf, 0, 0, 0);
            // x[b=sj*16+l15, ibase + it*16 + quad*4 + r] from LDS (bf16, 8B read)
            bf16x4 xr = *reinterpret_cast<const bf16x4*>(
                &smem[(sj * 16 + l15) * 136 + it * 16 + quad * 4]);
            float p = (cf[0] + wex0) * (float)xr[0] + (cf[1] + wex1) * (float)xr[1]
                    + (cf[2] + wex2) * (float)xr[2] + (cf[3] + wex3) * (float)xr[3];
            p += __shfl_xor(p, 16);
            p += __shfl_xor(p, 32);
            if (lane < 16) oacc[(wave * 4 + c) * 128 + sj * 16 + l15] += p;
        }
    }

    // ---- dbW MFMA + bias (only the y==0 i-split blocks contribute these)
    if (blockIdx.y == 0) {
        __syncthreads();
        const float* ab = dbW + (size_t)(otile + l15) * ZDsz + quad * 8;
        bf16x8 afrag[4];
        #pragma unroll
        for (int k = 0; k < 4; ++k) {
            float4 lo = *reinterpret_cast<const float4*>(ab + k * 32);
            float4 hi = *reinterpret_cast<const float4*>(ab + k * 32 + 4);
            afrag[k][0]=(__bf16)lo.x; afrag[k][1]=(__bf16)lo.y;
            afrag[k][2]=(__bf16)lo.z; afrag[k][3]=(__bf16)lo.w;
            afrag[k][4]=(__bf16)hi.x; afrag[k][5]=(__bf16)hi.y;
            afrag[k][6]=(__bf16)hi.z; afrag[k][7]=(__bf16)hi.w;
        }
        float4 bbv  = *reinterpret_cast<const float4*>(bb  + otile + quad * 4);
        float4 dbbv = *reinterpret_cast<const float4*>(dbb + otile + quad * 4);
        float bias0 = ratio * bbv.x + dbbv.x, bias1 = ratio * bbv.y + dbbv.y;
        float bias2 = ratio * bbv.z + dbbv.z, bias3 = ratio * bbv.w + dbbv.w;
        #pragma unroll
        for (int u = 0; u < 2; ++u) {
            int sj = wave * 2 + u;
            floatx4 cf = {0.f, 0.f, 0.f, 0.f};
            #pragma unroll
            for (int k = 0; k < 4; ++k)
                cf = __builtin_amdgcn_mfma_f32_16x16x32_bf16(afrag[k], bfrag[sj][k], cf, 0, 0, 0);
            oacc[(quad * 4 + 0) * 128 + sj * 16 + l15] += cf[0] + bias0;
            oacc[(quad * 4 + 1) * 128 + sj * 16 + l15] += cf[1] + bias1;
            oacc[(quad * 4 + 2) * 128 + sj * 16 + l15] += cf[2] + bias2;
            oacc[(quad * 4 + 3) * 128 + sj * 16 + l15] += cf[3] + bias3;
        }
    }
    __syncthreads();

    // ---- flush: 8 i-split blocks add into out (pre-zeroed by memset)
    {
        int b  = t >> 1;
        int og = (t & 1) * 8;
        #pragma unroll
        for (int j = 0; j < 8; ++j)
            atomicAdd(&out[(size_t)b * OUTsz + otile + og + j],
                      one_a * oacc[(og + j) * 128 + b]);
    }
}

extern "C" void kernel_launch(void* const* d_in, const int* in_sizes, int n_in,
                              void* d_out, int out_size, void* d_ws, size_t ws_size,
                              hipStream_t stream) {
    (void)in_sizes; (void)n_in; (void)d_ws; (void)ws_size;
    const float* x   = (const float*)d_in[0];
    const float* z   = (const float*)d_in[1];
    const float* W   = (const float*)d_in[2];
    const float* dwW = (const float*)d_in[3];
    const float* dwb = (const float*)d_in[4];
    const float* bb  = (const float*)d_in[5];
    const float* dbW = (const float*)d_in[6];
    const float* dbb = (const float*)d_in[7];
    const float* s   = (const float*)d_in[8];
    float* out = (float*)d_out;

    hipMemsetAsync(out, 0, (size_t)out_size * sizeof(float), stream);
    hyper_fused_kernel<<<dim3(OUTsz / 16, 8), 256, 0, stream>>>(
        x, z, W, dwW, dwb, bb, dbW, dbb, s, out);
}